// Round 19
// baseline (364.691 us; speedup 1.0000x reference)
//
#include <hip/hip_runtime.h>

typedef __attribute__((ext_vector_type(4))) float f32x4;
typedef __attribute__((ext_vector_type(8))) short bf16x8;

#define SEQ    2048
#define HD     64
#define NBH    32      // B*H
#define MTOK   4096    // B*S
#define DMODEL 1024
#define QBLK   128
#define C1 0.180336880f   /* 0.125 * log2(e) — folded into Q at the QKV epilogue */
#define C2 11.5415603f    /* 8.0  * log2(e)  (fixed softmax max M0 = 8) */

__device__ __forceinline__ unsigned short f2b(float f) {
  unsigned int u = __float_as_uint(f);
  u += 0x7fffu + ((u >> 16) & 1u);
  return (unsigned short)(u >> 16);
}
__device__ __forceinline__ float b2f(unsigned short s) {
  return __uint_as_float(((unsigned int)s) << 16);
}
__device__ __forceinline__ unsigned int cvtpk_bf16(float lo, float hi) {
  unsigned int r;
  asm("v_cvt_pk_bf16_f32 %0, %1, %2" : "=v"(r) : "v"(lo), "v"(hi));
  return r;
}
__device__ __forceinline__ void gload16(const void* g, void* l) {
  __builtin_amdgcn_global_load_lds(
      (const __attribute__((address_space(1))) unsigned int*)g,
      (__attribute__((address_space(3))) unsigned int*)l, 16, 0, 0);
}

// ---------- merged: x f32 -> bf16 (bid < 4096) and W transposes (bid >= 4096) ----------
__global__ __launch_bounds__(256) void k_prep(const float* __restrict__ x,
                                              unsigned short* __restrict__ xb,
                                              const float* __restrict__ Wq,
                                              const float* __restrict__ Wk,
                                              const float* __restrict__ Wv,
                                              const float* __restrict__ Wo,
                                              unsigned short* __restrict__ Wqkv,
                                              unsigned short* __restrict__ Wot) {
  __shared__ float tile[64 * 65];
  int bid = blockIdx.x, t = threadIdx.x;
  if (bid < 4096) {
    int i = bid * 256 + t;
    float4 v = ((const float4*)x)[i];
    ushort4 o;
    o.x = f2b(v.x); o.y = f2b(v.y); o.z = f2b(v.z); o.w = f2b(v.w);
    ((ushort4*)xb)[i] = o;
    return;
  }
  int e2 = bid - 4096;
  int z = e2 >> 8, rem = e2 & 255;
  int bi = rem >> 4, bj = rem & 15;
  const float* W = (z == 0) ? Wq : (z == 1) ? Wk : (z == 2) ? Wv : Wo;
  unsigned short* Wt = (z == 3) ? Wot : Wqkv + (size_t)z * DMODEL * DMODEL;
  for (int p = 0; p < 16; p++) {
    int e = p * 256 + t;
    int r = e >> 6, c = e & 63;
    tile[r * 65 + c] = W[(size_t)(bi * 64 + r) * DMODEL + bj * 64 + c];
  }
  __syncthreads();
  for (int p = 0; p < 16; p++) {
    int e = p * 256 + t;
    int n = e >> 6, k = e & 63;
    Wt[(size_t)(bj * 64 + n) * DMODEL + bi * 64 + k] = f2b(tile[k * 65 + n]);
  }
}

// ---------- GEMM C = A[M,K] * Bt[N,K]^T, 128x128 tile, BK=64, swizzled LDS ----------
// MODE 1: Q columns (which==0) are scaled by C1 so QK^T emerges softmax-pre-scaled.
template <int MODE>
__global__ __launch_bounds__(256) void k_gemm_bt(
    const unsigned short* __restrict__ A, const unsigned short* __restrict__ Bt,
    int M, int N, int K,
    const float* __restrict__ bias0, const float* __restrict__ bias1,
    const float* __restrict__ bias2,
    float* __restrict__ Cf,
    unsigned short* __restrict__ Qo, unsigned short* __restrict__ Ko,
    unsigned short* __restrict__ Vo) {
  __shared__ unsigned short As[128 * 64];
  __shared__ unsigned short Bs[128 * 64];
  int bm = blockIdx.x, bn = blockIdx.y;
  int tid = threadIdx.x;
  int w = tid >> 6, lane = tid & 63;
  int lg = lane >> 4, lc = lane & 15;
  int wm = (w >> 1) * 64, wn = (w & 1) * 64;
  f32x4 acc[4][4];
  for (int a = 0; a < 4; a++)
    for (int b = 0; b < 4; b++) acc[a][b] = (f32x4){0.f, 0.f, 0.f, 0.f};
  const unsigned short* ag = A + (size_t)(bm * 128) * K;
  const unsigned short* bg = Bt + (size_t)(bn * 128) * K;
  for (int k0 = 0; k0 < K; k0 += 64) {
    __syncthreads();
    for (int p = 0; p < 4; p++) {
      int c = (w * 4 + p) * 64 + lane;
      int r = c >> 3, ch = (c & 7) ^ (r & 7);   // inverse-swizzled source column
      gload16(ag + (size_t)r * K + k0 + ch * 8, &As[c * 8]);
      gload16(bg + (size_t)r * K + k0 + ch * 8, &Bs[c * 8]);
    }
    __syncthreads();
    for (int kk = 0; kk < 2; kk++) {
      bf16x8 av[4], bv[4];
      for (int mi = 0; mi < 4; mi++) {
        int row = wm + mi * 16 + lc;
        av[mi] = *(const bf16x8*)&As[row * 64 + ((kk * 32 + lg * 8) ^ ((row & 7) << 3))];
      }
      for (int ni = 0; ni < 4; ni++) {
        int row = wn + ni * 16 + lc;
        bv[ni] = *(const bf16x8*)&Bs[row * 64 + ((kk * 32 + lg * 8) ^ ((row & 7) << 3))];
      }
      for (int mi = 0; mi < 4; mi++)
        for (int ni = 0; ni < 4; ni++)
          acc[mi][ni] = __builtin_amdgcn_mfma_f32_16x16x32_bf16(av[mi], bv[ni], acc[mi][ni], 0, 0, 0);
    }
  }
  for (int mi = 0; mi < 4; mi++) {
    for (int i = 0; i < 4; i++) {
      int row = bm * 128 + wm + mi * 16 + 4 * lg + i;
      for (int ni = 0; ni < 4; ni++) {
        int col = bn * 128 + wn + ni * 16 + lc;
        float v = acc[mi][ni][i];
        if (MODE == 0) {
          Cf[(size_t)row * N + col] = v + bias0[col];
        } else {
          int which = col >> 10, hcol = col & 1023;
          const float* bb = which == 0 ? bias0 : (which == 1 ? bias1 : bias2);
          unsigned short* dst = which == 0 ? Qo : (which == 1 ? Ko : Vo);
          int b = row >> 11, s = row & 2047;
          int h = hcol >> 6, d = hcol & 63;
          float vv = v + bb[hcol];
          if (which == 0) vv *= C1;          // fold softmax scale into Q
          dst[(((size_t)(b * 16 + h)) * SEQ + s) * HD + d] = f2b(vv);
        }
      }
    }
  }
}

// ---------- merged: V transpose (x<32) and qr precompute (x>=32, bf16 out, pre-scaled) ----------
__global__ __launch_bounds__(256) void k_tvqr(const unsigned short* __restrict__ V,
                                              unsigned short* __restrict__ Vt,
                                              const unsigned short* __restrict__ Qb,
                                              const float* __restrict__ rel_emb,
                                              unsigned short* __restrict__ qr) {
  __shared__ unsigned short tile[64 * 72];
  __shared__ float relS[65 * 66];
  __shared__ unsigned short qS[32 * 64];
  int bh = blockIdx.y, t = threadIdx.x;
  if (blockIdx.x < 32) {
    int s0 = blockIdx.x * 64;
    for (int p = 0; p < 16; p++) {
      int e = p * 256 + t;
      int r = e >> 6, c = e & 63;
      tile[r * 72 + c] = V[(((size_t)bh) * SEQ + s0 + r) * HD + c];
    }
    __syncthreads();
    for (int p = 0; p < 16; p++) {
      int e = p * 256 + t;
      int d = e >> 6, j = e & 63;
      Vt[(((size_t)bh) * HD + d) * SEQ + s0 + j] = tile[j * 72 + d];
    }
  } else {
    int s0 = (blockIdx.x - 32) * 32;
    for (int i = t; i < 65 * 64; i += 256) relS[(i >> 6) * 66 + (i & 63)] = rel_emb[i];
    for (int i = t; i < 32 * 64; i += 256) qS[i] = Qb[((size_t)bh * SEQ + s0) * HD + i];
    __syncthreads();
    for (int e = t; e < 32 * 65; e += 256) {
      int sl = e / 65, r = e % 65;
      float acc = 0.f;
      for (int d = 0; d < 64; d++) acc += b2f(qS[sl * 64 + d]) * relS[r * 66 + d];
      qr[((size_t)bh * SEQ + s0 + sl) * 65 + r] = f2b(acc);
    }
  }
}

// ---------- flash attention: r14 KVBLK=64 body (48.6 KB LDS -> 3 blocks/CU), pre-scaled Q,
//            split-K via blockIdx.z (SPLIT=2: fixed-max partials just add; no rescale).
// LAW: K-loop global access ONLY via STAGE->barrier DMA; partial writes in epilogue.
template <int SPLIT>
__global__ __launch_bounds__(512, 6) void k_attn(const unsigned short* __restrict__ Qb,
                                                 const unsigned short* __restrict__ Kb,
                                                 const unsigned short* __restrict__ Vtb,
                                                 const unsigned short* __restrict__ qr,
                                                 unsigned short* __restrict__ ctx,
                                                 float* __restrict__ po,
                                                 float* __restrict__ pl) {
  __shared__ unsigned short Ks[64 * 64];    // [key][hd], row-swizzled
  __shared__ unsigned short Vts[64 * 64];   // [d][key], row-swizzled
  __shared__ unsigned short Ps[8][16 * 64]; // per-wave P tile [qrow][key], swizzled
  __shared__ unsigned short qrs[QBLK * 65]; // bf16 pre-scaled qr tile (16.6 KB)
  int bh = blockIdx.x, qt = blockIdx.y;     // XCD = linear%8 = bh%8 -> K/V L2-resident
  int half = (SPLIT == 2) ? blockIdx.z : 0;
  int kbase = half * (SEQ / SPLIT) / 64;    // in units of 64-key tiles
  int tid = threadIdx.x, w = tid >> 6, lane = tid & 63;
  int lg = lane >> 4, lc = lane & 15;
  int q0 = qt * QBLK, qw = q0 + w * 16;

  // stage qr tile (bf16, uint pairs; (bh*SEQ+q0)*65 even -> 4B aligned)
  {
    const unsigned int* src = (const unsigned int*)(qr + ((size_t)bh * SEQ + q0) * 65);
    for (int i = tid; i < QBLK * 65 / 2; i += 512) ((unsigned int*)qrs)[i] = src[i];
  }
  // Q fragments (wave owns rows qw..qw+15) — Q pre-scaled by C1
  bf16x8 aq[2];
  {
    const unsigned short* qp = Qb + ((size_t)bh * SEQ + qw + lc) * HD + lg * 8;
    aq[0] = *(const bf16x8*)qp;
    aq[1] = *(const bf16x8*)(qp + 32);
  }
  f32x4 o[4];
  float l[4];
  for (int n = 0; n < 4; n++) o[n] = (f32x4){0.f, 0.f, 0.f, 0.f};
  for (int i = 0; i < 4; i++) l[i] = 0.f;
  __syncthreads();   // qrs ready

  // clip-constant relative-bias terms per owned row (pre-scaled qr, subtract C2)
  float blo[4], bhi[4];
  for (int i = 0; i < 4; i++) {
    int rl = w * 16 + 4 * lg + i;
    blo[i] = b2f(qrs[rl * 65])      - C2;
    bhi[i] = b2f(qrs[rl * 65 + 64]) - C2;
  }

  for (int kt = 0; kt < (SEQ / 64) / SPLIT; kt++) {
    int k0 = (kbase + kt) * 64;
    const unsigned short* kg = Kb + ((size_t)bh * SEQ + k0) * HD;
    const unsigned short* vg = Vtb + ((size_t)bh * HD) * SEQ + k0;
    {
      int c = tid;                              // 512 16B-slots per tile, 1 per thread
      int r = c >> 3, ch = (c & 7) ^ (r & 7);   // inverse-swizzled source column
      gload16(kg + (size_t)r * HD + ch * 8, &Ks[c * 8]);
      gload16(vg + (size_t)r * SEQ + ch * 8, &Vts[c * 8]);
    }
    __syncthreads();   // K/V tile staged

    // QK^T (pre-scaled)
    f32x4 s[4];
    #pragma unroll
    for (int n = 0; n < 4; n++) s[n] = (f32x4){0.f, 0.f, 0.f, 0.f};
    __builtin_amdgcn_s_setprio(1);
    #pragma unroll
    for (int n = 0; n < 4; n++) {
      int row = n * 16 + lc;
      #pragma unroll
      for (int kk = 0; kk < 2; kk++) {
        bf16x8 bk = *(const bf16x8*)&Ks[row * 64 + ((kk * 32 + lg * 8) ^ ((row & 7) << 3))];
        s[n] = __builtin_amdgcn_mfma_f32_16x16x32_bf16(aq[kk], bk, s[n], 0, 0, 0);
      }
    }
    __builtin_amdgcn_s_setprio(0);

    // fixed-max softmax numerator: p = exp2(s + bf), bf = qr_scaled - C2
    int dw = qw - k0;
    bool gather = (dw >= -32) && (dw <= 80);   // wave-uniform partial-clip band
    #pragma unroll
    for (int n = 0; n < 4; n++)
      #pragma unroll
      for (int i = 0; i < 4; i++) {
        float bf;
        if (gather) {
          int rl = w * 16 + 4 * lg + i;
          int rel = rl + q0 - k0 - n * 16 - lc;
          rel = rel < -32 ? -32 : (rel > 32 ? 32 : rel);
          bf = b2f(qrs[rl * 65 + rel + 32]) - C2;
        } else {
          bf = (dw < 0) ? blo[i] : bhi[i];
        }
        float p = __builtin_amdgcn_exp2f(s[n][i] + bf);
        s[n][i] = p;
        l[i] += p;
      }

    // pack P (16 rows) to per-wave LDS tile, swizzled, cvt_pk pairs
    #pragma unroll
    for (int n = 0; n < 4; n++)
      #pragma unroll
      for (int i = 0; i < 4; i += 2) {
        unsigned int u = cvtpk_bf16(s[n][i], s[n][i + 1]);
        int r0 = 4 * lg + i, r1 = r0 + 1;
        Ps[w][r0 * 64 + ((n * 16 + lc) ^ ((r0 & 7) << 3))] = (unsigned short)u;
        Ps[w][r1 * 64 + ((n * 16 + lc) ^ ((r1 & 7) << 3))] = (unsigned short)(u >> 16);
      }

    // PV
    __builtin_amdgcn_s_setprio(1);
    #pragma unroll
    for (int kk = 0; kk < 2; kk++) {
      bf16x8 ap = *(const bf16x8*)&Ps[w][lc * 64 + ((kk * 32 + lg * 8) ^ ((lc & 7) << 3))];
      #pragma unroll
      for (int n = 0; n < 4; n++) {
        int row = n * 16 + lc;
        bf16x8 bv = *(const bf16x8*)&Vts[row * 64 + ((kk * 32 + lg * 8) ^ ((row & 7) << 3))];
        o[n] = __builtin_amdgcn_mfma_f32_16x16x32_bf16(ap, bv, o[n], 0, 0, 0);
      }
    }
    __builtin_amdgcn_s_setprio(0);
    __syncthreads();   // all waves done reading this tile before next STAGE
  }

  for (int i = 0; i < 4; i++) {
    float t = l[i];
    t += __shfl_xor(t, 1);
    t += __shfl_xor(t, 2);
    t += __shfl_xor(t, 4);
    t += __shfl_xor(t, 8);
    int row = qw + 4 * lg + i;
    if (SPLIT == 2) {
      size_t pbase = (((size_t)half * NBH + bh) * SEQ + row) * HD;
      for (int n = 0; n < 4; n++) po[pbase + n * 16 + lc] = o[n][i];
      if (lc == 0) pl[((size_t)half * NBH + bh) * SEQ + row] = t;
    } else {
      float inv = 1.f / t;
      int b = bh >> 4, h = bh & 15;
      size_t base = ((size_t)(b * SEQ + row)) * DMODEL + h * HD;
      for (int n = 0; n < 4; n++) ctx[base + n * 16 + lc] = f2b(o[n][i] * inv);
    }
  }
}

// ---------- combine split-K partials: ctx = (o0+o1)/(l0+l1) ----------
__global__ __launch_bounds__(256) void k_comb(const float* __restrict__ po,
                                              const float* __restrict__ pl,
                                              unsigned short* __restrict__ ctx) {
  size_t g = (size_t)blockIdx.x * 256 + threadIdx.x;   // one thread per 4 elements
  size_t e = g * 4;
  int d = (int)(e & 63);
  size_t bhq = e >> 6;
  int q = (int)(bhq & (SEQ - 1));
  int bh = (int)(bhq >> 11);
  float4 a = *(const float4*)(po + bhq * HD + d);
  float4 c = *(const float4*)(po + (size_t)NBH * SEQ * HD + bhq * HD + d);
  float lt = pl[bhq] + pl[(size_t)NBH * SEQ + bhq];
  float inv = 1.f / lt;
  int b = bh >> 4, h = bh & 15;
  ushort4 o;
  o.x = f2b((a.x + c.x) * inv);
  o.y = f2b((a.y + c.y) * inv);
  o.z = f2b((a.z + c.z) * inv);
  o.w = f2b((a.w + c.w) * inv);
  *(ushort4*)(ctx + ((size_t)(b * SEQ + q)) * DMODEL + h * HD + d) = o;
}

extern "C" void kernel_launch(void* const* d_in, const int* in_sizes, int n_in,
                              void* d_out, int out_size, void* d_ws, size_t ws_size,
                              hipStream_t stream) {
  const float* x   = (const float*)d_in[0];
  const float* Wq  = (const float*)d_in[1];
  const float* bq  = (const float*)d_in[2];
  const float* Wk  = (const float*)d_in[3];
  const float* bk  = (const float*)d_in[4];
  const float* Wv  = (const float*)d_in[5];
  const float* bv  = (const float*)d_in[6];
  const float* Wo  = (const float*)d_in[7];
  const float* bo  = (const float*)d_in[8];
  const float* rel = (const float*)d_in[9];
  float* out = (float*)d_out;

  char* ws = (char*)d_ws;
  size_t off = 0;
  auto carve = [&](size_t bytes) -> void* {
    void* p = ws + off;
    off += (bytes + 255) & ~(size_t)255;
    return p;
  };
  unsigned short* xb   = (unsigned short*)carve((size_t)MTOK * DMODEL * 2);
  unsigned short* Wqkv = (unsigned short*)carve((size_t)3 * DMODEL * DMODEL * 2);
  unsigned short* Wot  = (unsigned short*)carve((size_t)DMODEL * DMODEL * 2);
  unsigned short* Qb   = (unsigned short*)carve((size_t)NBH * SEQ * HD * 2);
  unsigned short* Kb   = (unsigned short*)carve((size_t)NBH * SEQ * HD * 2);
  unsigned short* Vb   = (unsigned short*)carve((size_t)NBH * SEQ * HD * 2);
  unsigned short* Vtb  = (unsigned short*)carve((size_t)NBH * SEQ * HD * 2);
  unsigned short* qr   = (unsigned short*)carve((size_t)NBH * SEQ * 65 * 2);
  unsigned short* ctx  = (unsigned short*)carve((size_t)MTOK * DMODEL * 2);
  float*          po   = (float*)carve((size_t)2 * NBH * SEQ * HD * 4);
  float*          pl   = (float*)carve((size_t)2 * NBH * SEQ * 4);
  bool split = (off <= ws_size);   // fall back to single-K if workspace is too small

  k_prep<<<4096 + 1024, 256, 0, stream>>>(x, xb, Wq, Wk, Wv, Wo, Wqkv, Wot);
  k_gemm_bt<1><<<dim3(32, 24), 256, 0, stream>>>(xb, Wqkv, MTOK, 3 * DMODEL, DMODEL,
                                                 bq, bk, bv, nullptr, Qb, Kb, Vb);
  k_tvqr<<<dim3(96, 32), 256, 0, stream>>>(Vb, Vtb, Qb, rel, qr);
  if (split) {
    k_attn<2><<<dim3(NBH, SEQ / QBLK, 2), 512, 0, stream>>>(Qb, Kb, Vtb, qr, ctx, po, pl);
    k_comb<<<(NBH * SEQ * HD / 4) / 256, 256, 0, stream>>>(po, pl, ctx);
  } else {
    k_attn<1><<<dim3(NBH, SEQ / QBLK), 512, 0, stream>>>(Qb, Kb, Vtb, qr, ctx, po, pl);
  }
  k_gemm_bt<0><<<dim3(32, 8), 256, 0, stream>>>(ctx, Wot, MTOK, DMODEL, DMODEL,
                                                bo, nullptr, nullptr, out,
                                                nullptr, nullptr, nullptr);
}

// Round 20
// 172.799 us; speedup vs baseline: 2.1105x; 2.1105x over previous
//
#include <hip/hip_runtime.h>

typedef __attribute__((ext_vector_type(4))) float f32x4;
typedef __attribute__((ext_vector_type(8))) short bf16x8;

#define SEQ    2048
#define HD     64
#define NBH    32      // B*H
#define MTOK   4096    // B*S
#define DMODEL 1024
#define QBLK   128
#define C1 0.180336880f   /* 0.125 * log2(e) — folded into Q at the QKV epilogue */
#define C2 11.5415603f    /* 8.0  * log2(e)  (fixed softmax max M0 = 8) */

__device__ __forceinline__ unsigned short f2b(float f) {
  unsigned int u = __float_as_uint(f);
  u += 0x7fffu + ((u >> 16) & 1u);
  return (unsigned short)(u >> 16);
}
__device__ __forceinline__ float b2f(unsigned short s) {
  return __uint_as_float(((unsigned int)s) << 16);
}
__device__ __forceinline__ unsigned int cvtpk_bf16(float lo, float hi) {
  unsigned int r;
  asm("v_cvt_pk_bf16_f32 %0, %1, %2" : "=v"(r) : "v"(lo), "v"(hi));
  return r;
}
__device__ __forceinline__ void gload16(const void* g, void* l) {
  __builtin_amdgcn_global_load_lds(
      (const __attribute__((address_space(1))) unsigned int*)g,
      (__attribute__((address_space(3))) unsigned int*)l, 16, 0, 0);
}

// ---------- merged: x f32 -> bf16 (bid < 4096) and W transposes (bid >= 4096) ----------
__global__ __launch_bounds__(256) void k_prep(const float* __restrict__ x,
                                              unsigned short* __restrict__ xb,
                                              const float* __restrict__ Wq,
                                              const float* __restrict__ Wk,
                                              const float* __restrict__ Wv,
                                              const float* __restrict__ Wo,
                                              unsigned short* __restrict__ Wqkv,
                                              unsigned short* __restrict__ Wot) {
  __shared__ float tile[64 * 65];
  int bid = blockIdx.x, t = threadIdx.x;
  if (bid < 4096) {
    int i = bid * 256 + t;
    float4 v = ((const float4*)x)[i];
    ushort4 o;
    o.x = f2b(v.x); o.y = f2b(v.y); o.z = f2b(v.z); o.w = f2b(v.w);
    ((ushort4*)xb)[i] = o;
    return;
  }
  int e2 = bid - 4096;
  int z = e2 >> 8, rem = e2 & 255;
  int bi = rem >> 4, bj = rem & 15;
  const float* W = (z == 0) ? Wq : (z == 1) ? Wk : (z == 2) ? Wv : Wo;
  unsigned short* Wt = (z == 3) ? Wot : Wqkv + (size_t)z * DMODEL * DMODEL;
  for (int p = 0; p < 16; p++) {
    int e = p * 256 + t;
    int r = e >> 6, c = e & 63;
    tile[r * 65 + c] = W[(size_t)(bi * 64 + r) * DMODEL + bj * 64 + c];
  }
  __syncthreads();
  for (int p = 0; p < 16; p++) {
    int e = p * 256 + t;
    int n = e >> 6, k = e & 63;
    Wt[(size_t)(bj * 64 + n) * DMODEL + bi * 64 + k] = f2b(tile[k * 65 + n]);
  }
}

// ---------- GEMM C = A[M,K] * Bt[N,K]^T, 128x128 tile, BK=64, swizzled LDS ----------
// MODE 1: Q columns (which==0) are scaled by C1 so QK^T emerges softmax-pre-scaled.
template <int MODE>
__global__ __launch_bounds__(256) void k_gemm_bt(
    const unsigned short* __restrict__ A, const unsigned short* __restrict__ Bt,
    int M, int N, int K,
    const float* __restrict__ bias0, const float* __restrict__ bias1,
    const float* __restrict__ bias2,
    float* __restrict__ Cf,
    unsigned short* __restrict__ Qo, unsigned short* __restrict__ Ko,
    unsigned short* __restrict__ Vo) {
  __shared__ unsigned short As[128 * 64];
  __shared__ unsigned short Bs[128 * 64];
  int bm = blockIdx.x, bn = blockIdx.y;
  int tid = threadIdx.x;
  int w = tid >> 6, lane = tid & 63;
  int lg = lane >> 4, lc = lane & 15;
  int wm = (w >> 1) * 64, wn = (w & 1) * 64;
  f32x4 acc[4][4];
  for (int a = 0; a < 4; a++)
    for (int b = 0; b < 4; b++) acc[a][b] = (f32x4){0.f, 0.f, 0.f, 0.f};
  const unsigned short* ag = A + (size_t)(bm * 128) * K;
  const unsigned short* bg = Bt + (size_t)(bn * 128) * K;
  for (int k0 = 0; k0 < K; k0 += 64) {
    __syncthreads();
    for (int p = 0; p < 4; p++) {
      int c = (w * 4 + p) * 64 + lane;
      int r = c >> 3, ch = (c & 7) ^ (r & 7);   // inverse-swizzled source column
      gload16(ag + (size_t)r * K + k0 + ch * 8, &As[c * 8]);
      gload16(bg + (size_t)r * K + k0 + ch * 8, &Bs[c * 8]);
    }
    __syncthreads();
    for (int kk = 0; kk < 2; kk++) {
      bf16x8 av[4], bv[4];
      for (int mi = 0; mi < 4; mi++) {
        int row = wm + mi * 16 + lc;
        av[mi] = *(const bf16x8*)&As[row * 64 + ((kk * 32 + lg * 8) ^ ((row & 7) << 3))];
      }
      for (int ni = 0; ni < 4; ni++) {
        int row = wn + ni * 16 + lc;
        bv[ni] = *(const bf16x8*)&Bs[row * 64 + ((kk * 32 + lg * 8) ^ ((row & 7) << 3))];
      }
      for (int mi = 0; mi < 4; mi++)
        for (int ni = 0; ni < 4; ni++)
          acc[mi][ni] = __builtin_amdgcn_mfma_f32_16x16x32_bf16(av[mi], bv[ni], acc[mi][ni], 0, 0, 0);
    }
  }
  for (int mi = 0; mi < 4; mi++) {
    for (int i = 0; i < 4; i++) {
      int row = bm * 128 + wm + mi * 16 + 4 * lg + i;
      for (int ni = 0; ni < 4; ni++) {
        int col = bn * 128 + wn + ni * 16 + lc;
        float v = acc[mi][ni][i];
        if (MODE == 0) {
          Cf[(size_t)row * N + col] = v + bias0[col];
        } else {
          int which = col >> 10, hcol = col & 1023;
          const float* bb = which == 0 ? bias0 : (which == 1 ? bias1 : bias2);
          unsigned short* dst = which == 0 ? Qo : (which == 1 ? Ko : Vo);
          int b = row >> 11, s = row & 2047;
          int h = hcol >> 6, d = hcol & 63;
          float vv = v + bb[hcol];
          if (which == 0) vv *= C1;          // fold softmax scale into Q
          dst[(((size_t)(b * 16 + h)) * SEQ + s) * HD + d] = f2b(vv);
        }
      }
    }
  }
}

// ---------- merged: V transpose (x<32) and qr precompute (x>=32, bf16 out, pre-scaled) ----------
__global__ __launch_bounds__(256) void k_tvqr(const unsigned short* __restrict__ V,
                                              unsigned short* __restrict__ Vt,
                                              const unsigned short* __restrict__ Qb,
                                              const float* __restrict__ rel_emb,
                                              unsigned short* __restrict__ qr) {
  __shared__ unsigned short tile[64 * 72];
  __shared__ float relS[65 * 66];
  __shared__ unsigned short qS[32 * 64];
  int bh = blockIdx.y, t = threadIdx.x;
  if (blockIdx.x < 32) {
    int s0 = blockIdx.x * 64;
    for (int p = 0; p < 16; p++) {
      int e = p * 256 + t;
      int r = e >> 6, c = e & 63;
      tile[r * 72 + c] = V[(((size_t)bh) * SEQ + s0 + r) * HD + c];
    }
    __syncthreads();
    for (int p = 0; p < 16; p++) {
      int e = p * 256 + t;
      int d = e >> 6, j = e & 63;
      Vt[(((size_t)bh) * HD + d) * SEQ + s0 + j] = tile[j * 72 + d];
    }
  } else {
    int s0 = (blockIdx.x - 32) * 32;
    for (int i = t; i < 65 * 64; i += 256) relS[(i >> 6) * 66 + (i & 63)] = rel_emb[i];
    for (int i = t; i < 32 * 64; i += 256) qS[i] = Qb[((size_t)bh * SEQ + s0) * HD + i];
    __syncthreads();
    for (int e = t; e < 32 * 65; e += 256) {
      int sl = e / 65, r = e % 65;
      float acc = 0.f;
      for (int d = 0; d < 64; d++) acc += b2f(qS[sl * 64 + d]) * relS[r * 66 + d];
      qr[((size_t)bh * SEQ + s0 + sl) * 65 + r] = f2b(acc);
    }
  }
}

// ---------- flash attention: r18 final (KVBLK=128, pre-scaled Q, bf16 qrs LDS, XCD grid) ----------
// Per kt: STAGE 128 keys (2 K + 2 V DMA slots/thread) -> barrier -> wave body twice
// (sub-tiles of 64 keys) -> barrier. LAW: K-loop global access ONLY via STAGE DMA.
__global__ __launch_bounds__(512, 4) void k_attn(const unsigned short* __restrict__ Qb,
                                                 const unsigned short* __restrict__ Kb,
                                                 const unsigned short* __restrict__ Vtb,
                                                 const unsigned short* __restrict__ qr,
                                                 unsigned short* __restrict__ ctx) {
  __shared__ unsigned short Ks[128 * 64];   // [key 0..127][hd], row-swizzled (8 chunks/row)
  __shared__ unsigned short Vts[64 * 128];  // [d][key 0..127], row-swizzled (16 chunks/row, XOR low 3 bits)
  __shared__ unsigned short Ps[8][16 * 64]; // per-wave P tile [qrow][key], swizzled
  __shared__ unsigned short qrs[QBLK * 65]; // bf16 pre-scaled qr tile (16.6 KB)
  int bh = blockIdx.x, qt = blockIdx.y;     // XCD = linear%8 = bh%8 -> K/V L2-resident
  int tid = threadIdx.x, w = tid >> 6, lane = tid & 63;
  int lg = lane >> 4, lc = lane & 15;
  int q0 = qt * QBLK, qw = q0 + w * 16;

  // stage qr tile (bf16, uint pairs; (bh*SEQ+q0)*65 even -> 4B aligned)
  {
    const unsigned int* src = (const unsigned int*)(qr + ((size_t)bh * SEQ + q0) * 65);
    for (int i = tid; i < QBLK * 65 / 2; i += 512) ((unsigned int*)qrs)[i] = src[i];
  }
  // Q fragments (wave owns rows qw..qw+15) — Q is pre-scaled by C1
  bf16x8 aq[2];
  {
    const unsigned short* qp = Qb + ((size_t)bh * SEQ + qw + lc) * HD + lg * 8;
    aq[0] = *(const bf16x8*)qp;
    aq[1] = *(const bf16x8*)(qp + 32);
  }
  f32x4 o[4];
  float l[4];
  for (int n = 0; n < 4; n++) o[n] = (f32x4){0.f, 0.f, 0.f, 0.f};
  for (int i = 0; i < 4; i++) l[i] = 0.f;
  __syncthreads();   // qrs ready

  // clip-constant relative-bias terms per owned row (pre-scaled qr, just subtract C2)
  float blo[4], bhi[4];
  for (int i = 0; i < 4; i++) {
    int rl = w * 16 + 4 * lg + i;
    blo[i] = b2f(qrs[rl * 65])      - C2;
    bhi[i] = b2f(qrs[rl * 65 + 64]) - C2;
  }

  for (int kt = 0; kt < SEQ / 128; kt++) {
    int k0 = kt * 128;
    const unsigned short* kg = Kb + ((size_t)bh * SEQ + k0) * HD;
    const unsigned short* vg = Vtb + ((size_t)bh * HD) * SEQ + k0;
    #pragma unroll
    for (int p = 0; p < 2; p++) {
      int idx = p * 512 + tid;                       // 1024 K-slots + 1024 V-slots
      int kr = idx >> 3, kch = (idx & 7) ^ (kr & 7); // Ks: 8 chunks/row
      gload16(kg + (size_t)kr * HD + kch * 8, &Ks[idx * 8]);
      int vr = idx >> 4, vch = (idx & 15) ^ (vr & 7); // Vts: 16 chunks/row, XOR low 3 bits
      gload16(vg + (size_t)vr * SEQ + vch * 8, &Vts[idx * 8]);
    }
    __syncthreads();   // K/V tile staged

    #pragma unroll
    for (int sub = 0; sub < 2; sub++) {
      int k0s = k0 + sub * 64;

      // QK^T (pre-scaled): s[n] covers keys k0s + n*16+lc for the wave's 16 q-rows
      f32x4 s[4];
      #pragma unroll
      for (int n = 0; n < 4; n++) s[n] = (f32x4){0.f, 0.f, 0.f, 0.f};
      __builtin_amdgcn_s_setprio(1);
      #pragma unroll
      for (int n = 0; n < 4; n++) {
        int row = sub * 64 + n * 16 + lc;
        #pragma unroll
        for (int kk = 0; kk < 2; kk++) {
          bf16x8 bk = *(const bf16x8*)&Ks[row * 64 + ((kk * 32 + lg * 8) ^ ((row & 7) << 3))];
          s[n] = __builtin_amdgcn_mfma_f32_16x16x32_bf16(aq[kk], bk, s[n], 0, 0, 0);
        }
      }
      __builtin_amdgcn_s_setprio(0);

      // fixed-max softmax numerator: p = exp2(s + bf), bf = qr_scaled - C2
      int dw = qw - k0s;
      bool gather = (dw >= -32) && (dw <= 80);   // wave-uniform partial-clip band
      #pragma unroll
      for (int n = 0; n < 4; n++)
        #pragma unroll
        for (int i = 0; i < 4; i++) {
          float bf;
          if (gather) {
            int rl = w * 16 + 4 * lg + i;
            int rel = rl + q0 - k0s - n * 16 - lc;
            rel = rel < -32 ? -32 : (rel > 32 ? 32 : rel);
            bf = b2f(qrs[rl * 65 + rel + 32]) - C2;
          } else {
            bf = (dw < 0) ? blo[i] : bhi[i];
          }
          float p = __builtin_amdgcn_exp2f(s[n][i] + bf);
          s[n][i] = p;
          l[i] += p;
        }

      // pack P (16 rows) to per-wave LDS tile, swizzled, cvt_pk pairs
      #pragma unroll
      for (int n = 0; n < 4; n++)
        #pragma unroll
        for (int i = 0; i < 4; i += 2) {
          unsigned int u = cvtpk_bf16(s[n][i], s[n][i + 1]);
          int r0 = 4 * lg + i, r1 = r0 + 1;
          Ps[w][r0 * 64 + ((n * 16 + lc) ^ ((r0 & 7) << 3))] = (unsigned short)u;
          Ps[w][r1 * 64 + ((n * 16 + lc) ^ ((r1 & 7) << 3))] = (unsigned short)(u >> 16);
        }

      // PV over this sub-tile's 64 keys
      __builtin_amdgcn_s_setprio(1);
      #pragma unroll
      for (int kk = 0; kk < 2; kk++) {
        bf16x8 ap = *(const bf16x8*)&Ps[w][lc * 64 + ((kk * 32 + lg * 8) ^ ((lc & 7) << 3))];
        #pragma unroll
        for (int n = 0; n < 4; n++) {
          int vrow = n * 16 + lc;
          int vcol = sub * 64 + kk * 32 + lg * 8;
          bf16x8 bv = *(const bf16x8*)&Vts[vrow * 128 + (vcol ^ ((vrow & 7) << 3))];
          o[n] = __builtin_amdgcn_mfma_f32_16x16x32_bf16(ap, bv, o[n], 0, 0, 0);
        }
      }
      __builtin_amdgcn_s_setprio(0);
    }
    __syncthreads();   // all waves done reading this tile before next STAGE
  }

  int b = bh >> 4, h = bh & 15;
  for (int i = 0; i < 4; i++) {
    float t = l[i];
    t += __shfl_xor(t, 1);
    t += __shfl_xor(t, 2);
    t += __shfl_xor(t, 4);
    t += __shfl_xor(t, 8);
    float inv = 1.f / t;
    int row = qw + 4 * lg + i;
    size_t base = ((size_t)(b * SEQ + row)) * DMODEL + h * HD;
    for (int n = 0; n < 4; n++) ctx[base + n * 16 + lc] = f2b(o[n][i] * inv);
  }
}

extern "C" void kernel_launch(void* const* d_in, const int* in_sizes, int n_in,
                              void* d_out, int out_size, void* d_ws, size_t ws_size,
                              hipStream_t stream) {
  const float* x   = (const float*)d_in[0];
  const float* Wq  = (const float*)d_in[1];
  const float* bq  = (const float*)d_in[2];
  const float* Wk  = (const float*)d_in[3];
  const float* bk  = (const float*)d_in[4];
  const float* Wv  = (const float*)d_in[5];
  const float* bv  = (const float*)d_in[6];
  const float* Wo  = (const float*)d_in[7];
  const float* bo  = (const float*)d_in[8];
  const float* rel = (const float*)d_in[9];
  float* out = (float*)d_out;

  char* ws = (char*)d_ws;
  size_t off = 0;
  auto carve = [&](size_t bytes) -> void* {
    void* p = ws + off;
    off += (bytes + 255) & ~(size_t)255;
    return p;
  };
  unsigned short* xb   = (unsigned short*)carve((size_t)MTOK * DMODEL * 2);
  unsigned short* Wqkv = (unsigned short*)carve((size_t)3 * DMODEL * DMODEL * 2);
  unsigned short* Wot  = (unsigned short*)carve((size_t)DMODEL * DMODEL * 2);
  unsigned short* Qb   = (unsigned short*)carve((size_t)NBH * SEQ * HD * 2);
  unsigned short* Kb   = (unsigned short*)carve((size_t)NBH * SEQ * HD * 2);
  unsigned short* Vb   = (unsigned short*)carve((size_t)NBH * SEQ * HD * 2);
  unsigned short* Vtb  = (unsigned short*)carve((size_t)NBH * SEQ * HD * 2);
  unsigned short* qr   = (unsigned short*)carve((size_t)NBH * SEQ * 65 * 2);
  unsigned short* ctx  = (unsigned short*)carve((size_t)MTOK * DMODEL * 2);

  k_prep<<<4096 + 1024, 256, 0, stream>>>(x, xb, Wq, Wk, Wv, Wo, Wqkv, Wot);
  k_gemm_bt<1><<<dim3(32, 24), 256, 0, stream>>>(xb, Wqkv, MTOK, 3 * DMODEL, DMODEL,
                                                 bq, bk, bv, nullptr, Qb, Kb, Vb);
  k_tvqr<<<dim3(96, 32), 256, 0, stream>>>(Vb, Vtb, Qb, rel, qr);
  k_attn<<<dim3(NBH, SEQ / QBLK), 512, 0, stream>>>(Qb, Kb, Vtb, qr, ctx);
  k_gemm_bt<0><<<dim3(32, 8), 256, 0, stream>>>(ctx, Wot, MTOK, DMODEL, DMODEL,
                                                bo, nullptr, nullptr, out,
                                                nullptr, nullptr, nullptr);
}